// Round 2
// baseline (603.432 us; speedup 1.0000x reference)
//
#include <hip/hip_runtime.h>
#include <stdint.h>

// SIREN MLP 3->256->256->256->256->3, N=524288, fp32 in/out.
// Hidden layers: bf16 MFMA 16x16x32, orientation D[chan][pt], W held in
// 128 VGPRs per wave (loaded coalesced from pre-permuted ws, no LDS, no
// barrier). h ping-pongs in 32KB LDS with conflict-free 16B-unit layout
// u=(kc*4+rt)*64+q*16+n16. 7 barriers/block total.

#define OMEGA 30.0f

typedef float    f32x4 __attribute__((ext_vector_type(4)));
typedef short    s16x8 __attribute__((ext_vector_type(8)));
typedef uint32_t u32x4 __attribute__((ext_vector_type(4)));

__device__ __forceinline__ float bf16_to_f32(uint16_t u) {
    uint32_t b = ((uint32_t)u) << 16;
    return __builtin_bit_cast(float, b);
}
__device__ __forceinline__ uint16_t f32_to_bf16(float f) {
    uint32_t u = __builtin_bit_cast(uint32_t, f);
    u += 0x7FFFu + ((u >> 16) & 1u);   // RNE
    return (uint16_t)(u >> 16);
}
__device__ __forceinline__ uint32_t pack_bf16x2(float lo, float hi) {
    return (uint32_t)f32_to_bf16(lo) | ((uint32_t)f32_to_bf16(hi) << 16);
}

// W1..W3 (256x256 fp32, row-major (out,in)) -> bf16 A-fragment order:
// halfword idx = (((l*8+kc)*16 + (c>>4))*64 + q*16 + (c&15))*8 + j
// so a wave's frag load for (kc, chan-tile) is 64 lane-consecutive 16B.
__global__ void convert_weights(const float* __restrict__ W1,
                                const float* __restrict__ W2,
                                const float* __restrict__ W3,
                                uint16_t* __restrict__ wsb) {
    int tid = blockIdx.x * blockDim.x + threadIdx.x;   // 0..196607
    int l = tid >> 16;
    int r = tid & 65535;
    int c = r >> 8;        // out-chan
    int k = r & 255;       // in-chan
    const float* W = (l == 0) ? W1 : (l == 1) ? W2 : W3;
    int kc = k >> 5, q = (k >> 3) & 3, j = k & 7;
    wsb[(((l * 8 + kc) * 16 + (c >> 4)) * 64 + q * 16 + (c & 15)) * 8 + j] =
        f32_to_bf16(W[c * 256 + k]);
}

// 256 threads = 4 waves, 64 points/block. Wave wid owns chans wid*64..+63
// (4 chan-tiles as MFMA M) x all 64 pts (4 pt-tiles as MFMA N).
// acc 64 VGPR + Wf 128 VGPR. LDS = h only, 32KB -> 2 blocks/CU.
__global__ __launch_bounds__(256, 2) void siren_main(
    const float* __restrict__ x,
    const float* __restrict__ W0, const float* __restrict__ b0,
    const float* __restrict__ b1, const float* __restrict__ b2,
    const float* __restrict__ b3,
    const float* __restrict__ W4, const float* __restrict__ b4,
    const uint16_t* __restrict__ Wb,   // permuted W1..W3, 384KB
    float* __restrict__ out)
{
    __shared__ uint16_t h_lds[2048 * 8];   // 32 KB: unit u -> h[pt][chan-octet]

    const int tid  = threadIdx.x;
    const int lane = tid & 63;
    const int wid  = tid >> 6;
    const int n16  = lane & 15;
    const int q    = lane >> 4;
    const int p0   = blockIdx.x * 64;

    // ---- issue layer-1 W fragment loads (hidden under layer-0 compute) ----
    s16x8 Wf[8][4];    // [kc][chan-tile]
    #pragma unroll
    for (int kc = 0; kc < 8; ++kc)
        #pragma unroll
        for (int t = 0; t < 4; ++t)
            Wf[kc][t] = *(const s16x8*)(Wb + ((kc * 16 + wid * 4 + t) * 64 + lane) * 8);

    // ---------------- Layer 0 (fp32): h1 = sin(30*(W0 x + b0)) -------------
    {
        float xv[4][3];
        #pragma unroll
        for (int rt = 0; rt < 4; ++rt) {
            const float* xp = x + (p0 + rt * 16 + n16) * 3;
            xv[rt][0] = xp[0]; xv[rt][1] = xp[1]; xv[rt][2] = xp[2];
        }
        #pragma unroll
        for (int oo = 0; oo < 2; ++oo) {
            const int octet = wid * 8 + oo * 4 + q;      // chan-octet 0..31
            const float* w0r = W0 + octet * 24;
            float wv[24];
            #pragma unroll
            for (int i = 0; i < 24; ++i) wv[i] = w0r[i];
            float bb[8];
            #pragma unroll
            for (int i = 0; i < 8; ++i) bb[i] = b0[octet * 8 + i];
            const int kc0 = octet >> 2, q0 = octet & 3;
            #pragma unroll
            for (int rt = 0; rt < 4; ++rt) {
                u32x4 pk;
                #pragma unroll
                for (int j2 = 0; j2 < 4; ++j2) {
                    float za = OMEGA * (wv[(2*j2  )*3+0] * xv[rt][0] +
                                        wv[(2*j2  )*3+1] * xv[rt][1] +
                                        wv[(2*j2  )*3+2] * xv[rt][2] + bb[2*j2]);
                    float zb = OMEGA * (wv[(2*j2+1)*3+0] * xv[rt][0] +
                                        wv[(2*j2+1)*3+1] * xv[rt][1] +
                                        wv[(2*j2+1)*3+2] * xv[rt][2] + bb[2*j2+1]);
                    pk[j2] = pack_bf16x2(__sinf(za), __sinf(zb));
                }
                // lanes (n16,q): unit = const + q*16 + n16 -> conflict-free b128
                *(u32x4*)&h_lds[((kc0 * 4 + rt) * 64 + q0 * 16 + n16) * 8] = pk;
            }
        }
    }
    __syncthreads();

    // ---------------- Hidden layers (bf16 MFMA, D[chan][pt]) ---------------
    for (int l = 0; l < 3; ++l) {
        f32x4 acc[4][4] = {};   // [chan-tile t][pt-tile pt]

        #pragma unroll
        for (int kc = 0; kc < 8; ++kc) {
            s16x8 hf[4];        // B-frags: lane n16 = pt-in-tile, q = k-octet
            #pragma unroll
            for (int pt = 0; pt < 4; ++pt)
                hf[pt] = *(const s16x8*)&h_lds[((kc * 4 + pt) * 64 + lane) * 8];
            #pragma unroll
            for (int t = 0; t < 4; ++t)
                #pragma unroll
                for (int pt = 0; pt < 4; ++pt)
                    acc[t][pt] = __builtin_amdgcn_mfma_f32_16x16x32_bf16(
                        Wf[kc][t], hf[pt], acc[t][pt], 0, 0, 0);
        }
        __syncthreads();   // all h reads done before overwrite

        // prefetch next layer's W (drained at next barrier, hidden by sins)
        if (l < 2) {
            const uint16_t* wsl = Wb + (l + 1) * 65536;
            #pragma unroll
            for (int kc = 0; kc < 8; ++kc)
                #pragma unroll
                for (int t = 0; t < 4; ++t)
                    Wf[kc][t] = *(const s16x8*)(wsl + ((kc * 16 + wid * 4 + t) * 64 + lane) * 8);
        }

        // epilogue: bias + sin, write h_next in B-frag layout.
        // thread value (t,pt,r): chan = wid*64+t*16+q*4+r, pt_g = pt*16+n16
        const float* bl = (l == 0) ? b1 : (l == 1) ? b2 : b3;
        uint32_t* hw = (uint32_t*)h_lds;
        #pragma unroll
        for (int t = 0; t < 4; ++t) {
            f32x4 bv = *(const f32x4*)&bl[wid * 64 + t * 16 + q * 4];
            const int kcp = wid * 2 + (t >> 1);
            const int qp  = (t * 2 + (q >> 1)) & 3;
            #pragma unroll
            for (int pt = 0; pt < 4; ++pt) {
                float s0 = __sinf(acc[t][pt][0] + bv[0]);
                float s1 = __sinf(acc[t][pt][1] + bv[1]);
                float s2 = __sinf(acc[t][pt][2] + bv[2]);
                float s3 = __sinf(acc[t][pt][3] + bv[3]);
                int base = ((kcp * 4 + pt) * 64 + qp * 16 + n16) * 4 + (q & 1) * 2;
                hw[base + 0] = pack_bf16x2(s0, s1);   // r=0,1
                hw[base + 1] = pack_bf16x2(s2, s3);   // r=2,3
            }
        }
        __syncthreads();
    }

    // ---------------- Final layer (fp32): out = W4 h4 + b4 -----------------
    if (tid < 192) {
        const int p  = tid & 63;
        const int o  = __builtin_amdgcn_readfirstlane(tid >> 6);  // wave-uniform
        const int rt = p >> 4, nn = p & 15;
        const float* w4 = W4 + o * 256;
        float sum = b4[o];
        for (int kc = 0; kc < 8; ++kc) {
            #pragma unroll
            for (int qq = 0; qq < 4; ++qq) {
                s16x8 hv = *(const s16x8*)&h_lds[((kc * 4 + rt) * 64 + qq * 16 + nn) * 8];
                #pragma unroll
                for (int e = 0; e < 8; ++e)
                    sum += bf16_to_f32((uint16_t)hv[e]) * w4[kc * 32 + qq * 8 + e];
            }
        }
        out[(p0 + p) * 3 + o] = sum;
    }
}

extern "C" void kernel_launch(void* const* d_in, const int* in_sizes, int n_in,
                              void* d_out, int out_size, void* d_ws, size_t ws_size,
                              hipStream_t stream) {
    const float* x  = (const float*)d_in[0];
    const float* W0 = (const float*)d_in[1];
    const float* b0 = (const float*)d_in[2];
    const float* W1 = (const float*)d_in[3];
    const float* b1 = (const float*)d_in[4];
    const float* W2 = (const float*)d_in[5];
    const float* b2 = (const float*)d_in[6];
    const float* W3 = (const float*)d_in[7];
    const float* b3 = (const float*)d_in[8];
    const float* W4 = (const float*)d_in[9];
    const float* b4 = (const float*)d_in[10];
    float* outp     = (float*)d_out;
    uint16_t* wsb   = (uint16_t*)d_ws;   // 384KB

    hipLaunchKernelGGL(convert_weights, dim3(768), dim3(256), 0, stream,
                       W1, W2, W3, wsb);
    hipLaunchKernelGGL(siren_main, dim3(8192), dim3(256), 0, stream,
                       x, W0, b0, b1, b2, b3, W4, b4, wsb, outp);
}

// Round 3
// 346.013 us; speedup vs baseline: 1.7440x; 1.7440x over previous
//
#include <hip/hip_runtime.h>
#include <stdint.h>

// SIREN MLP 3->256->256->256->256->3, N=524288, fp32 in/out.
// Hidden layers: bf16 MFMA 16x16x32, orientation D[chan][pt]. W fragments
// stream global->VGPR via a small rotating double-buffer (Wbuf[2][2][4],
// 256B -> guaranteed SROA promotion; R2's Wf[8][4]=1KB was demoted to
// scratch = 1GB HBM spill traffic). h ping-pongs in 32KB LDS, conflict-free
// 16B-unit layout u=(kc*4+pt)*64+q*16+n16. Layer loop fully unrolled.

#define OMEGA 30.0f

typedef float    f32x4 __attribute__((ext_vector_type(4)));
typedef short    s16x8 __attribute__((ext_vector_type(8)));
typedef uint32_t u32x4 __attribute__((ext_vector_type(4)));

__device__ __forceinline__ float bf16_to_f32(uint16_t u) {
    uint32_t b = ((uint32_t)u) << 16;
    return __builtin_bit_cast(float, b);
}
__device__ __forceinline__ uint16_t f32_to_bf16(float f) {
    uint32_t u = __builtin_bit_cast(uint32_t, f);
    u += 0x7FFFu + ((u >> 16) & 1u);   // RNE
    return (uint16_t)(u >> 16);
}
__device__ __forceinline__ uint32_t pack_bf16x2(float lo, float hi) {
    return (uint32_t)f32_to_bf16(lo) | ((uint32_t)f32_to_bf16(hi) << 16);
}

// W1..W3 (256x256 fp32, row-major (out,in)) -> bf16 A-fragment order:
// halfword idx = (((l*8+kc)*16 + (c>>4))*64 + q*16 + (c&15))*8 + j
// so a wave's frag load for (kc, chan-tile) is 64 lane-consecutive 16B.
__global__ void convert_weights(const float* __restrict__ W1,
                                const float* __restrict__ W2,
                                const float* __restrict__ W3,
                                uint16_t* __restrict__ wsb) {
    int tid = blockIdx.x * blockDim.x + threadIdx.x;   // 0..196607
    int l = tid >> 16;
    int r = tid & 65535;
    int c = r >> 8;        // out-chan
    int k = r & 255;       // in-chan
    const float* W = (l == 0) ? W1 : (l == 1) ? W2 : W3;
    int kc = k >> 5, q = (k >> 3) & 3, j = k & 7;
    wsb[(((l * 8 + kc) * 16 + (c >> 4)) * 64 + q * 16 + (c & 15)) * 8 + j] =
        f32_to_bf16(W[c * 256 + k]);
}

// 256 threads = 4 waves, 64 points/block. Wave wid owns chans wid*64..+63
// (4 chan-tiles as MFMA M) x all 64 pts (4 pt-tiles as MFMA N).
// VGPR: Wbuf 64 + acc 64 + hf 16 + misc ~30 -> ~175. LDS 32KB -> 2 blk/CU.
__global__ __launch_bounds__(256, 2) void siren_main(
    const float* __restrict__ x,
    const float* __restrict__ W0, const float* __restrict__ b0,
    const float* __restrict__ b1, const float* __restrict__ b2,
    const float* __restrict__ b3,
    const float* __restrict__ W4, const float* __restrict__ b4,
    const uint16_t* __restrict__ Wb,   // permuted W1..W3, 384KB
    float* __restrict__ out)
{
    __shared__ uint16_t h_lds[2048 * 8];   // 32 KB

    const int tid  = threadIdx.x;
    const int lane = tid & 63;
    const int wid  = tid >> 6;
    const int n16  = lane & 15;
    const int q    = lane >> 4;
    const int p0   = blockIdx.x * 64;

    // ---------------- Layer 0 (fp32): h1 = sin(30*(W0 x + b0)) -------------
    {
        float xv[4][3];
        #pragma unroll
        for (int rt = 0; rt < 4; ++rt) {
            const float* xp = x + (p0 + rt * 16 + n16) * 3;
            xv[rt][0] = xp[0]; xv[rt][1] = xp[1]; xv[rt][2] = xp[2];
        }
        #pragma unroll
        for (int oo = 0; oo < 2; ++oo) {
            const int octet = wid * 8 + oo * 4 + q;      // chan-octet 0..31
            const float* w0r = W0 + octet * 24;
            float wv[24];
            #pragma unroll
            for (int i = 0; i < 24; ++i) wv[i] = w0r[i];
            float bb[8];
            #pragma unroll
            for (int i = 0; i < 8; ++i) bb[i] = b0[octet * 8 + i];
            const int kc0 = octet >> 2, q0 = octet & 3;
            #pragma unroll
            for (int rt = 0; rt < 4; ++rt) {
                u32x4 pk;
                #pragma unroll
                for (int j2 = 0; j2 < 4; ++j2) {
                    float za = OMEGA * (wv[(2*j2  )*3+0] * xv[rt][0] +
                                        wv[(2*j2  )*3+1] * xv[rt][1] +
                                        wv[(2*j2  )*3+2] * xv[rt][2] + bb[2*j2]);
                    float zb = OMEGA * (wv[(2*j2+1)*3+0] * xv[rt][0] +
                                        wv[(2*j2+1)*3+1] * xv[rt][1] +
                                        wv[(2*j2+1)*3+2] * xv[rt][2] + bb[2*j2+1]);
                    pk[j2] = pack_bf16x2(__sinf(za), __sinf(zb));
                }
                *(u32x4*)&h_lds[((kc0 * 4 + rt) * 64 + q0 * 16 + n16) * 8] = pk;
            }
        }
    }
    __syncthreads();

    // ---------------- Hidden layers (bf16 MFMA, D[chan][pt]) ---------------
    #pragma unroll
    for (int l = 0; l < 3; ++l) {
        const uint16_t* wsl = Wb + l * 65536;

        // rotating kc-pair double buffer of W fragments (256B -> SSA)
        s16x8 Wbuf[2][2][4];   // [buf][kc-in-pair][chan-tile]
        #pragma unroll
        for (int kc2 = 0; kc2 < 2; ++kc2)
            #pragma unroll
            for (int t = 0; t < 4; ++t)
                Wbuf[0][kc2][t] = *(const s16x8*)(wsl + ((kc2 * 16 + wid * 4 + t) * 64 + lane) * 8);

        f32x4 acc[4][4] = {};   // [chan-tile t][pt-tile pt]
        #pragma unroll
        for (int kp = 0; kp < 4; ++kp) {      // kc pair index
            const int cur = kp & 1, nxt = cur ^ 1;
            if (kp < 3) {                     // prefetch next pair under MFMA
                #pragma unroll
                for (int kc2 = 0; kc2 < 2; ++kc2)
                    #pragma unroll
                    for (int t = 0; t < 4; ++t)
                        Wbuf[nxt][kc2][t] = *(const s16x8*)(wsl +
                            (((kp * 2 + 2 + kc2) * 16 + wid * 4 + t) * 64 + lane) * 8);
            }
            #pragma unroll
            for (int kc2 = 0; kc2 < 2; ++kc2) {
                const int kc = kp * 2 + kc2;
                s16x8 hf[4];   // B-frags: lane n16 = pt-in-tile, q = k-octet
                #pragma unroll
                for (int pt = 0; pt < 4; ++pt)
                    hf[pt] = *(const s16x8*)&h_lds[((kc * 4 + pt) * 64 + lane) * 8];
                #pragma unroll
                for (int t = 0; t < 4; ++t)
                    #pragma unroll
                    for (int pt = 0; pt < 4; ++pt)
                        acc[t][pt] = __builtin_amdgcn_mfma_f32_16x16x32_bf16(
                            Wbuf[cur][kc2][t], hf[pt], acc[t][pt], 0, 0, 0);
            }
        }
        __syncthreads();   // all h reads done before overwrite

        // epilogue: bias + sin, write h_next in B-frag layout.
        // thread value (t,pt,r): chan = wid*64+t*16+q*4+r, pt_g = pt*16+n16
        const float* bl = (l == 0) ? b1 : (l == 1) ? b2 : b3;
        uint32_t* hw = (uint32_t*)h_lds;
        #pragma unroll
        for (int t = 0; t < 4; ++t) {
            f32x4 bv = *(const f32x4*)&bl[wid * 64 + t * 16 + q * 4];
            const int kcp = wid * 2 + (t >> 1);
            const int qp  = (t * 2 + (q >> 1)) & 3;
            #pragma unroll
            for (int pt = 0; pt < 4; ++pt) {
                float s0 = __sinf(acc[t][pt][0] + bv[0]);
                float s1 = __sinf(acc[t][pt][1] + bv[1]);
                float s2 = __sinf(acc[t][pt][2] + bv[2]);
                float s3 = __sinf(acc[t][pt][3] + bv[3]);
                int base = ((kcp * 4 + pt) * 64 + qp * 16 + n16) * 4 + (q & 1) * 2;
                hw[base + 0] = pack_bf16x2(s0, s1);   // r=0,1
                hw[base + 1] = pack_bf16x2(s2, s3);   // r=2,3
            }
        }
        __syncthreads();
    }

    // ---------------- Final layer (fp32): out = W4 h4 + b4 -----------------
    if (tid < 192) {
        const int p  = tid & 63;
        const int o  = __builtin_amdgcn_readfirstlane(tid >> 6);  // wave-uniform
        const int rt = p >> 4, nn = p & 15;
        const float* w4 = W4 + o * 256;
        float sum = b4[o];
        for (int kc = 0; kc < 8; ++kc) {
            #pragma unroll
            for (int qq = 0; qq < 4; ++qq) {
                s16x8 hv = *(const s16x8*)&h_lds[((kc * 4 + rt) * 64 + qq * 16 + nn) * 8];
                #pragma unroll
                for (int e = 0; e < 8; ++e)
                    sum += bf16_to_f32((uint16_t)hv[e]) * w4[kc * 32 + qq * 8 + e];
            }
        }
        out[(p0 + p) * 3 + o] = sum;
    }
}

extern "C" void kernel_launch(void* const* d_in, const int* in_sizes, int n_in,
                              void* d_out, int out_size, void* d_ws, size_t ws_size,
                              hipStream_t stream) {
    const float* x  = (const float*)d_in[0];
    const float* W0 = (const float*)d_in[1];
    const float* b0 = (const float*)d_in[2];
    const float* W1 = (const float*)d_in[3];
    const float* b1 = (const float*)d_in[4];
    const float* W2 = (const float*)d_in[5];
    const float* b2 = (const float*)d_in[6];
    const float* W3 = (const float*)d_in[7];
    const float* b3 = (const float*)d_in[8];
    const float* W4 = (const float*)d_in[9];
    const float* b4 = (const float*)d_in[10];
    float* outp     = (float*)d_out;
    uint16_t* wsb   = (uint16_t*)d_ws;   // 384KB

    hipLaunchKernelGGL(convert_weights, dim3(768), dim3(256), 0, stream,
                       W1, W2, W3, wsb);
    hipLaunchKernelGGL(siren_main, dim3(8192), dim3(256), 0, stream,
                       x, W0, b0, b1, b2, b3, W4, b4, wsb, outp);
}

// Round 4
// 328.672 us; speedup vs baseline: 1.8360x; 1.0528x over previous
//
#include <hip/hip_runtime.h>
#include <stdint.h>

// SIREN MLP 3->256->256->256->256->3, N=524288, fp32 in/out.
// Hidden layers: bf16 MFMA 16x16x32, D[chan][pt]. W streams global->VGPR via
// 256B rotating double-buffer (SROA-safe). h ping-pongs in 32KB LDS,
// conflict-free 16B-unit layout u=(kc*4+pt)*64+q*16+n16.
// R4: v_cvt_pk_bf16_f32 packs, 1/(2pi) folded into weights (bare v_sin_f32),
// final layer as MFMA vs zero-padded W4^T fragment.

typedef float    f32x4 __attribute__((ext_vector_type(4)));
typedef short    s16x8 __attribute__((ext_vector_type(8)));
typedef uint32_t u32x2 __attribute__((ext_vector_type(2)));
typedef uint32_t u32x4 __attribute__((ext_vector_type(4)));

#define INV2PI 0.15915494309189535f
#define L0SCALE 4.774648292756860f   /* 30/(2*pi) */
#define W4OFF 196608                 /* halfword offset of W4^T frag in ws */

__device__ __forceinline__ uint16_t f32_to_bf16(float f) {
    uint32_t u = __builtin_bit_cast(uint32_t, f);
    u += 0x7FFFu + ((u >> 16) & 1u);   // RNE
    return (uint16_t)(u >> 16);
}
__device__ __forceinline__ uint32_t pack_bf16x2(float lo, float hi) {
#if __has_builtin(__builtin_amdgcn_cvt_pk_bf16_f32)
    auto v = __builtin_amdgcn_cvt_pk_bf16_f32(lo, hi);   // lo -> low half
    return __builtin_bit_cast(uint32_t, v);
#else
    uint32_t a = __builtin_bit_cast(uint32_t, lo);
    uint32_t b = __builtin_bit_cast(uint32_t, hi);
    a += 0x7FFFu + ((a >> 16) & 1u);
    b += 0x7FFFu + ((b >> 16) & 1u);
    return (a >> 16) | (b & 0xFFFF0000u);
#endif
}
// sin with input in REVOLUTIONS (v_sin_f32); 1/(2pi) pre-folded into weights.
__device__ __forceinline__ float sin_rev(float r) {
    return __builtin_amdgcn_sinf(r);
}

// W1..W3 -> bf16 A-frag order, scaled by 1/(2pi):
//   hw idx = (((l*8+kc)*16 + (c>>4))*64 + q*16 + (c&15))*8 + j, k=kc*32+q*8+j
// W4 (3x256) -> zero-padded B-frag (16 out-cols, 3 used), unscaled:
//   hw idx = W4OFF + (kc*64 + lane)*8 + j; value = n16<3 ? W4[n16][kc*32+q*8+j] : 0
__global__ void convert_weights(const float* __restrict__ W1,
                                const float* __restrict__ W2,
                                const float* __restrict__ W3,
                                const float* __restrict__ W4,
                                uint16_t* __restrict__ wsb) {
    int tid = blockIdx.x * blockDim.x + threadIdx.x;
    if (tid < 196608) {
        int l = tid >> 16;
        int r = tid & 65535;
        int c = r >> 8;        // out-chan
        int k = r & 255;       // in-chan
        const float* W = (l == 0) ? W1 : (l == 1) ? W2 : W3;
        int kc = k >> 5, q = (k >> 3) & 3, j = k & 7;
        wsb[(((l * 8 + kc) * 16 + (c >> 4)) * 64 + q * 16 + (c & 15)) * 8 + j] =
            f32_to_bf16(W[c * 256 + k] * INV2PI);
    } else if (tid < 200704) {
        int e = tid - 196608;              // 0..4095
        int kc = e >> 9, lane = (e >> 3) & 63, j = e & 7;
        int n16 = lane & 15, q = lane >> 4;
        float v = (n16 < 3) ? W4[n16 * 256 + kc * 32 + q * 8 + j] : 0.0f;
        wsb[W4OFF + (kc * 64 + lane) * 8 + j] = f32_to_bf16(v);
    }
}

// 256 threads = 4 waves, 64 points/block. Wave wid owns chans wid*64..+63.
__global__ __launch_bounds__(256, 2) void siren_main(
    const float* __restrict__ x,
    const float* __restrict__ W0, const float* __restrict__ b0,
    const float* __restrict__ b1, const float* __restrict__ b2,
    const float* __restrict__ b3,
    const float* __restrict__ b4,
    const uint16_t* __restrict__ Wb,   // permuted W1..W3 + W4 frag
    float* __restrict__ out)
{
    __shared__ uint16_t h_lds[2048 * 8];   // 32 KB

    const int tid  = threadIdx.x;
    const int lane = tid & 63;
    const int wid  = tid >> 6;
    const int n16  = lane & 15;
    const int q    = lane >> 4;
    const int p0   = blockIdx.x * 64;

    // W4^T B-frags: constant all kernel, 32 VGPRs, loaded once (L2-resident).
    s16x8 W4f[8];
    #pragma unroll
    for (int kc = 0; kc < 8; ++kc)
        W4f[kc] = *(const s16x8*)(Wb + W4OFF + (kc * 64 + lane) * 8);

    // ------- Layer 0 (fp32): h1 = sin_rev( (30/2pi)*(W0 x + b0) ) ----------
    {
        float xv[4][3];
        #pragma unroll
        for (int rt = 0; rt < 4; ++rt) {
            const float* xp = x + (p0 + rt * 16 + n16) * 3;
            xv[rt][0] = xp[0]; xv[rt][1] = xp[1]; xv[rt][2] = xp[2];
        }
        #pragma unroll
        for (int oo = 0; oo < 2; ++oo) {
            const int octet = wid * 8 + oo * 4 + q;      // chan-octet 0..31
            const float* w0r = W0 + octet * 24;
            float wv[24];
            #pragma unroll
            for (int i = 0; i < 24; ++i) wv[i] = w0r[i] * L0SCALE;
            float bb[8];
            #pragma unroll
            for (int i = 0; i < 8; ++i) bb[i] = b0[octet * 8 + i] * L0SCALE;
            const int kc0 = octet >> 2, q0 = octet & 3;
            #pragma unroll
            for (int rt = 0; rt < 4; ++rt) {
                u32x4 pk;
                #pragma unroll
                for (int j2 = 0; j2 < 4; ++j2) {
                    float za = wv[(2*j2  )*3+0] * xv[rt][0] +
                               wv[(2*j2  )*3+1] * xv[rt][1] +
                               wv[(2*j2  )*3+2] * xv[rt][2] + bb[2*j2];
                    float zb = wv[(2*j2+1)*3+0] * xv[rt][0] +
                               wv[(2*j2+1)*3+1] * xv[rt][1] +
                               wv[(2*j2+1)*3+2] * xv[rt][2] + bb[2*j2+1];
                    pk[j2] = pack_bf16x2(sin_rev(za), sin_rev(zb));
                }
                *(u32x4*)&h_lds[((kc0 * 4 + rt) * 64 + q0 * 16 + n16) * 8] = pk;
            }
        }
    }
    __syncthreads();

    // ------- Hidden layers (bf16 MFMA, D[chan][pt]) -------------------------
    #pragma unroll
    for (int l = 0; l < 3; ++l) {
        const uint16_t* wsl = Wb + l * 65536;

        // rotating kc-pair double buffer of W fragments (256B -> SSA)
        s16x8 Wbuf[2][2][4];   // [buf][kc-in-pair][chan-tile]
        #pragma unroll
        for (int kc2 = 0; kc2 < 2; ++kc2)
            #pragma unroll
            for (int t = 0; t < 4; ++t)
                Wbuf[0][kc2][t] = *(const s16x8*)(wsl + ((kc2 * 16 + wid * 4 + t) * 64 + lane) * 8);

        f32x4 acc[4][4] = {};   // [chan-tile t][pt-tile pt]
        #pragma unroll
        for (int kp = 0; kp < 4; ++kp) {      // kc pair index
            const int cur = kp & 1, nxt = cur ^ 1;
            if (kp < 3) {                     // prefetch next pair under MFMA
                #pragma unroll
                for (int kc2 = 0; kc2 < 2; ++kc2)
                    #pragma unroll
                    for (int t = 0; t < 4; ++t)
                        Wbuf[nxt][kc2][t] = *(const s16x8*)(wsl +
                            (((kp * 2 + 2 + kc2) * 16 + wid * 4 + t) * 64 + lane) * 8);
            }
            #pragma unroll
            for (int kc2 = 0; kc2 < 2; ++kc2) {
                const int kc = kp * 2 + kc2;
                s16x8 hf[4];   // B-frags: lane n16 = pt-in-tile, q = k-octet
                #pragma unroll
                for (int pt = 0; pt < 4; ++pt)
                    hf[pt] = *(const s16x8*)&h_lds[((kc * 4 + pt) * 64 + lane) * 8];
                #pragma unroll
                for (int t = 0; t < 4; ++t)
                    #pragma unroll
                    for (int pt = 0; pt < 4; ++pt)
                        acc[t][pt] = __builtin_amdgcn_mfma_f32_16x16x32_bf16(
                            Wbuf[cur][kc2][t], hf[pt], acc[t][pt], 0, 0, 0);
            }
        }
        __syncthreads();   // all h reads done before overwrite

        // epilogue: bias (pre-scaled 1/2pi) + sin, write h_next in B-frag layout
        const float* bl = (l == 0) ? b1 : (l == 1) ? b2 : b3;
        uint32_t* hw = (uint32_t*)h_lds;
        #pragma unroll
        for (int t = 0; t < 4; ++t) {
            f32x4 bv = *(const f32x4*)&bl[wid * 64 + t * 16 + q * 4];
            bv *= INV2PI;
            const int kcp = wid * 2 + (t >> 1);
            const int qp  = (t * 2 + (q >> 1)) & 3;
            #pragma unroll
            for (int pt = 0; pt < 4; ++pt) {
                float s0 = sin_rev(acc[t][pt][0] + bv[0]);
                float s1 = sin_rev(acc[t][pt][1] + bv[1]);
                float s2 = sin_rev(acc[t][pt][2] + bv[2]);
                float s3 = sin_rev(acc[t][pt][3] + bv[3]);
                int base = ((kcp * 4 + pt) * 64 + qp * 16 + n16) * 4 + (q & 1) * 2;
                u32x2 w2 = { pack_bf16x2(s0, s1), pack_bf16x2(s2, s3) };
                *(u32x2*)&hw[base] = w2;   // 8B write, r=0..3
            }
        }
        __syncthreads();
    }

    // ------- Final layer via MFMA: out = W4 h4 + b4 -------------------------
    // h4 LDS frag doubles as A (m=pt): A/B share the lane->(idx,k) map.
    {
        f32x4 accF = {};
        #pragma unroll
        for (int kc = 0; kc < 8; ++kc) {
            s16x8 af = *(const s16x8*)&h_lds[((kc * 4 + wid) * 64 + lane) * 8];
            accF = __builtin_amdgcn_mfma_f32_16x16x32_bf16(af, W4f[kc], accF, 0, 0, 0);
        }
        // D: row=q*4+r -> pt-in-tile (tile wid), col=n16 -> out-chan (3 used)
        if (n16 < 3) {
            float bb4 = b4[n16];
            #pragma unroll
            for (int r = 0; r < 4; ++r)
                out[(p0 + wid * 16 + q * 4 + r) * 3 + n16] = accF[r] + bb4;
        }
    }
}

extern "C" void kernel_launch(void* const* d_in, const int* in_sizes, int n_in,
                              void* d_out, int out_size, void* d_ws, size_t ws_size,
                              hipStream_t stream) {
    const float* x  = (const float*)d_in[0];
    const float* W0 = (const float*)d_in[1];
    const float* b0 = (const float*)d_in[2];
    const float* W1 = (const float*)d_in[3];
    const float* b1 = (const float*)d_in[4];
    const float* W2 = (const float*)d_in[5];
    const float* b2 = (const float*)d_in[6];
    const float* W3 = (const float*)d_in[7];
    const float* b3 = (const float*)d_in[8];
    const float* W4 = (const float*)d_in[9];
    const float* b4 = (const float*)d_in[10];
    float* outp     = (float*)d_out;
    uint16_t* wsb   = (uint16_t*)d_ws;   // needs 402 KB

    hipLaunchKernelGGL(convert_weights, dim3(784), dim3(256), 0, stream,
                       W1, W2, W3, W4, wsb);
    hipLaunchKernelGGL(siren_main, dim3(8192), dim3(256), 0, stream,
                       x, W0, b0, b1, b2, b3, b4, wsb, outp);
}

// Round 5
// 299.572 us; speedup vs baseline: 2.0143x; 1.0971x over previous
//
#include <hip/hip_runtime.h>
#include <stdint.h>

// SIREN MLP 3->256->256->256->256->3, N=524288, fp32 in/out.
// Hidden layers: bf16 MFMA 16x16x32, D[chan][pt]. W streams global->VGPR via
// 256B rotating double-buffer (SROA-safe). h ping-pongs in 32KB LDS,
// conflict-free 16B-unit layout u=(kc*4+pt)*64+q*16+n16.
// R5: launch_bounds(256,3) -> 3 blocks/CU (was self-capped at 2); bias
// pre-loaded into MFMA accumulators (no epilogue adds); W4 frags loaded
// late to cut live registers during the main loops.

typedef float    f32x4 __attribute__((ext_vector_type(4)));
typedef short    s16x8 __attribute__((ext_vector_type(8)));
typedef uint32_t u32x2 __attribute__((ext_vector_type(2)));
typedef uint32_t u32x4 __attribute__((ext_vector_type(4)));

#define INV2PI 0.15915494309189535f
#define L0SCALE 4.774648292756860f   /* 30/(2*pi) */
#define W4OFF 196608                 /* halfword offset of W4^T frag in ws */

__device__ __forceinline__ uint16_t f32_to_bf16(float f) {
    uint32_t u = __builtin_bit_cast(uint32_t, f);
    u += 0x7FFFu + ((u >> 16) & 1u);   // RNE
    return (uint16_t)(u >> 16);
}
__device__ __forceinline__ uint32_t pack_bf16x2(float lo, float hi) {
#if __has_builtin(__builtin_amdgcn_cvt_pk_bf16_f32)
    auto v = __builtin_amdgcn_cvt_pk_bf16_f32(lo, hi);   // lo -> low half
    return __builtin_bit_cast(uint32_t, v);
#else
    uint32_t a = __builtin_bit_cast(uint32_t, lo);
    uint32_t b = __builtin_bit_cast(uint32_t, hi);
    a += 0x7FFFu + ((a >> 16) & 1u);
    b += 0x7FFFu + ((b >> 16) & 1u);
    return (a >> 16) | (b & 0xFFFF0000u);
#endif
}
// sin with input in REVOLUTIONS (v_sin_f32); 1/(2pi) pre-folded into weights.
__device__ __forceinline__ float sin_rev(float r) {
    return __builtin_amdgcn_sinf(r);
}

// W1..W3 -> bf16 A-frag order, scaled by 1/(2pi):
//   hw idx = (((l*8+kc)*16 + (c>>4))*64 + q*16 + (c&15))*8 + j, k=kc*32+q*8+j
// W4 (3x256) -> zero-padded B-frag (16 out-cols, 3 used), unscaled:
//   hw idx = W4OFF + (kc*64 + lane)*8 + j; value = n16<3 ? W4[n16][kc*32+q*8+j] : 0
__global__ void convert_weights(const float* __restrict__ W1,
                                const float* __restrict__ W2,
                                const float* __restrict__ W3,
                                const float* __restrict__ W4,
                                uint16_t* __restrict__ wsb) {
    int tid = blockIdx.x * blockDim.x + threadIdx.x;
    if (tid < 196608) {
        int l = tid >> 16;
        int r = tid & 65535;
        int c = r >> 8;        // out-chan
        int k = r & 255;       // in-chan
        const float* W = (l == 0) ? W1 : (l == 1) ? W2 : W3;
        int kc = k >> 5, q = (k >> 3) & 3, j = k & 7;
        wsb[(((l * 8 + kc) * 16 + (c >> 4)) * 64 + q * 16 + (c & 15)) * 8 + j] =
            f32_to_bf16(W[c * 256 + k] * INV2PI);
    } else if (tid < 200704) {
        int e = tid - 196608;              // 0..4095
        int kc = e >> 9, lane = (e >> 3) & 63, j = e & 7;
        int n16 = lane & 15, q = lane >> 4;
        float v = (n16 < 3) ? W4[n16 * 256 + kc * 32 + q * 8 + j] : 0.0f;
        wsb[W4OFF + (kc * 64 + lane) * 8 + j] = f32_to_bf16(v);
    }
}

// 256 threads = 4 waves, 64 points/block. Wave wid owns chans wid*64..+63.
// (256,3): 3 waves/SIMD -> 3 blocks/CU; unified VGPR cap 170/wave.
__global__ __launch_bounds__(256, 3) void siren_main(
    const float* __restrict__ x,
    const float* __restrict__ W0, const float* __restrict__ b0,
    const float* __restrict__ b1, const float* __restrict__ b2,
    const float* __restrict__ b3,
    const float* __restrict__ b4,
    const uint16_t* __restrict__ Wb,   // permuted W1..W3 + W4 frag
    float* __restrict__ out)
{
    __shared__ uint16_t h_lds[2048 * 8];   // 32 KB

    const int tid  = threadIdx.x;
    const int lane = tid & 63;
    const int wid  = tid >> 6;
    const int n16  = lane & 15;
    const int q    = lane >> 4;
    const int p0   = blockIdx.x * 64;

    // ------- Layer 0 (fp32): h1 = sin_rev( (30/2pi)*(W0 x + b0) ) ----------
    {
        float xv[4][3];
        #pragma unroll
        for (int rt = 0; rt < 4; ++rt) {
            const float* xp = x + (p0 + rt * 16 + n16) * 3;
            xv[rt][0] = xp[0]; xv[rt][1] = xp[1]; xv[rt][2] = xp[2];
        }
        #pragma unroll
        for (int oo = 0; oo < 2; ++oo) {
            const int octet = wid * 8 + oo * 4 + q;      // chan-octet 0..31
            const float* w0r = W0 + octet * 24;
            float wv[24];
            #pragma unroll
            for (int i = 0; i < 24; ++i) wv[i] = w0r[i] * L0SCALE;
            float bb[8];
            #pragma unroll
            for (int i = 0; i < 8; ++i) bb[i] = b0[octet * 8 + i] * L0SCALE;
            const int kc0 = octet >> 2, q0 = octet & 3;
            #pragma unroll
            for (int rt = 0; rt < 4; ++rt) {
                u32x4 pk;
                #pragma unroll
                for (int j2 = 0; j2 < 4; ++j2) {
                    float za = wv[(2*j2  )*3+0] * xv[rt][0] +
                               wv[(2*j2  )*3+1] * xv[rt][1] +
                               wv[(2*j2  )*3+2] * xv[rt][2] + bb[2*j2];
                    float zb = wv[(2*j2+1)*3+0] * xv[rt][0] +
                               wv[(2*j2+1)*3+1] * xv[rt][1] +
                               wv[(2*j2+1)*3+2] * xv[rt][2] + bb[2*j2+1];
                    pk[j2] = pack_bf16x2(sin_rev(za), sin_rev(zb));
                }
                *(u32x4*)&h_lds[((kc0 * 4 + rt) * 64 + q0 * 16 + n16) * 8] = pk;
            }
        }
    }
    __syncthreads();

    // ------- Hidden layers (bf16 MFMA, D[chan][pt]) -------------------------
    #pragma unroll
    for (int l = 0; l < 3; ++l) {
        const uint16_t* wsl = Wb + l * 65536;
        const float* bl = (l == 0) ? b1 : (l == 1) ? b2 : b3;

        // rotating kc-pair double buffer of W fragments (256B -> SSA)
        s16x8 Wbuf[2][2][4];   // [buf][kc-in-pair][chan-tile]
        #pragma unroll
        for (int kc2 = 0; kc2 < 2; ++kc2)
            #pragma unroll
            for (int t = 0; t < 4; ++t)
                Wbuf[0][kc2][t] = *(const s16x8*)(wsl + ((kc2 * 16 + wid * 4 + t) * 64 + lane) * 8);

        // acc init = bias (pre-scaled): rides the MFMA C input, no epilogue add
        f32x4 acc[4][4];       // [chan-tile t][pt-tile pt]
        #pragma unroll
        for (int t = 0; t < 4; ++t) {
            f32x4 bv = *(const f32x4*)&bl[wid * 64 + t * 16 + q * 4];
            bv *= INV2PI;
            #pragma unroll
            for (int pt = 0; pt < 4; ++pt) acc[t][pt] = bv;
        }

        #pragma unroll
        for (int kp = 0; kp < 4; ++kp) {      // kc pair index
            const int cur = kp & 1, nxt = cur ^ 1;
            if (kp < 3) {                     // prefetch next pair under MFMA
                #pragma unroll
                for (int kc2 = 0; kc2 < 2; ++kc2)
                    #pragma unroll
                    for (int t = 0; t < 4; ++t)
                        Wbuf[nxt][kc2][t] = *(const s16x8*)(wsl +
                            (((kp * 2 + 2 + kc2) * 16 + wid * 4 + t) * 64 + lane) * 8);
            }
            #pragma unroll
            for (int kc2 = 0; kc2 < 2; ++kc2) {
                const int kc = kp * 2 + kc2;
                s16x8 hf[4];   // B-frags: lane n16 = pt-in-tile, q = k-octet
                #pragma unroll
                for (int pt = 0; pt < 4; ++pt)
                    hf[pt] = *(const s16x8*)&h_lds[((kc * 4 + pt) * 64 + lane) * 8];
                #pragma unroll
                for (int t = 0; t < 4; ++t)
                    #pragma unroll
                    for (int pt = 0; pt < 4; ++pt)
                        acc[t][pt] = __builtin_amdgcn_mfma_f32_16x16x32_bf16(
                            Wbuf[cur][kc2][t], hf[pt], acc[t][pt], 0, 0, 0);
            }
        }
        __syncthreads();   // all h reads done before overwrite

        // epilogue: sin (bias already in acc), write h_next in B-frag layout
        uint32_t* hw = (uint32_t*)h_lds;
        #pragma unroll
        for (int t = 0; t < 4; ++t) {
            const int kcp = wid * 2 + (t >> 1);
            const int qp  = (t * 2 + (q >> 1)) & 3;
            #pragma unroll
            for (int pt = 0; pt < 4; ++pt) {
                float s0 = sin_rev(acc[t][pt][0]);
                float s1 = sin_rev(acc[t][pt][1]);
                float s2 = sin_rev(acc[t][pt][2]);
                float s3 = sin_rev(acc[t][pt][3]);
                int base = ((kcp * 4 + pt) * 64 + qp * 16 + n16) * 4 + (q & 1) * 2;
                u32x2 w2 = { pack_bf16x2(s0, s1), pack_bf16x2(s2, s3) };
                *(u32x2*)&hw[base] = w2;   // 8B write, r=0..3
            }
        }
        __syncthreads();
    }

    // ------- Final layer via MFMA: out = W4 h4 + b4 -------------------------
    // h4 LDS frag doubles as A (m=pt); W4^T frags loaded late (L2-resident)
    // to keep them out of the live range of the main loops.
    {
        float bb4 = (n16 < 3) ? b4[n16] : 0.0f;
        f32x4 accF = { bb4, bb4, bb4, bb4 };
        #pragma unroll
        for (int kc = 0; kc < 8; ++kc) {
            s16x8 w4f = *(const s16x8*)(Wb + W4OFF + (kc * 64 + lane) * 8);
            s16x8 af  = *(const s16x8*)&h_lds[((kc * 4 + wid) * 64 + lane) * 8];
            accF = __builtin_amdgcn_mfma_f32_16x16x32_bf16(af, w4f, accF, 0, 0, 0);
        }
        // D: row=q*4+r -> pt-in-tile (tile wid), col=n16 -> out-chan (3 used)
        if (n16 < 3) {
            #pragma unroll
            for (int r = 0; r < 4; ++r)
                out[(p0 + wid * 16 + q * 4 + r) * 3 + n16] = accF[r];
        }
    }
}

extern "C" void kernel_launch(void* const* d_in, const int* in_sizes, int n_in,
                              void* d_out, int out_size, void* d_ws, size_t ws_size,
                              hipStream_t stream) {
    const float* x  = (const float*)d_in[0];
    const float* W0 = (const float*)d_in[1];
    const float* b0 = (const float*)d_in[2];
    const float* W1 = (const float*)d_in[3];
    const float* b1 = (const float*)d_in[4];
    const float* W2 = (const float*)d_in[5];
    const float* b2 = (const float*)d_in[6];
    const float* W3 = (const float*)d_in[7];
    const float* b3 = (const float*)d_in[8];
    const float* W4 = (const float*)d_in[9];
    const float* b4 = (const float*)d_in[10];
    float* outp     = (float*)d_out;
    uint16_t* wsb   = (uint16_t*)d_ws;   // needs 402 KB

    hipLaunchKernelGGL(convert_weights, dim3(784), dim3(256), 0, stream,
                       W1, W2, W3, W4, wsb);
    hipLaunchKernelGGL(siren_main, dim3(8192), dim3(256), 0, stream,
                       x, W0, b0, b1, b2, b3, b4, wsb, outp);
}